// Round 5
// baseline (223.758 us; speedup 1.0000x reference)
//
#include <hip/hip_runtime.h>
#include <stdint.h>

// ---------------------------------------------------------------------------
// HeteNet round 7: NT=2 timesteps per block (grid 1024 = one fully-resident
// round), register prefetch of ts1 inputs during ts0 compute.
// x staged UNSORTED (row = token id) so staging overlaps the sort; L1 reads
// via per-tile token map tokR[] held in registers (static indexing).
// Carries round-6 algebra: gfrag bias-fold (L1 K=96 -> 2 LDS ks + reg gfrag),
// one-hot L2 bias MFMA, te-outer weight hoisting, <=3 fix-up chains/layer.
// Kernels: prep -> main. ws holds wp (130 KiB).
// ---------------------------------------------------------------------------

typedef float v4f __attribute__((ext_vector_type(4)));
typedef short v8s __attribute__((ext_vector_type(8)));
typedef short v4s __attribute__((ext_vector_type(4)));
typedef float v4fa __attribute__((ext_vector_type(4), aligned(4)));

#define XS_STR 72      // LDS x stride (elems), 144 B
#define HS_STR 136     // LDS h stride (elems), 272 B
#define WP2_OFF  30720 // 60 frag-blocks * 512 shorts
#define WP3_OFF  51200 // + 40 * 512
#define WPB2_OFF 56320 // + 10 * 512 ; L2-bias frags: 20 blocks
#define NT 2           // timesteps per block

#define SEL4(te, a0, a1, a2, a3) \
    ((te) < 2 ? ((te) == 0 ? (a0) : (a1)) : ((te) == 2 ? (a2) : (a3)))

static __device__ __forceinline__ short f2bf(float f) {
    union { __bf16 b; short s; } u;
    u.b = (__bf16)f;   // native RNE convert
    return u.s;
}

static __device__ __forceinline__ v4s pack4r(const v4f a) {
    v4s r;
    r[0] = f2bf(fmaxf(a[0], 0.f));
    r[1] = f2bf(fmaxf(a[1], 0.f));
    r[2] = f2bf(fmaxf(a[2], 0.f));
    r[3] = f2bf(fmaxf(a[3], 0.f));
    return r;
}

// ---------------- weight prep: fragment-ready bf16 layout ----------------
// Frag-block = 512 shorts: lane l holds out-feat n=l&15, k=(l>>4)*8+j.
// L1 frags carry bias at k==68 (multiplied by gfrag's 1.0 slot).
// WPB2 region: L2 bias frags, nonzero only at local k==0 (one-hot onef).
__global__ void prep_kernel(const float* __restrict__ W1, const float* __restrict__ cW1,
                            const float* __restrict__ W2, const float* __restrict__ cW2,
                            const float* __restrict__ W3, const float* __restrict__ cW3,
                            const float* __restrict__ b1, const float* __restrict__ cb1,
                            const float* __restrict__ b2, const float* __restrict__ cb2,
                            short* __restrict__ wp) {
    int b = blockIdx.x, lane = threadIdx.x;
    int nl = lane & 15, quad = lane >> 4;
    short frag[8];
    if (b < 60) {
        int e = b / 12, rem = b % 12, ks = rem / 4, nt = rem % 4;
        int n = nt * 16 + nl;
#pragma unroll
        for (int j = 0; j < 8; j++) {
            int k = ks * 32 + quad * 8 + j;
            float v = 0.f;
            if (k < 68)       v = (e < 4) ? W1[(e * 68 + k) * 64 + n] : cW1[k * 64 + n];
            else if (k == 68) v = (e < 4) ? b1[e * 64 + n] : cb1[n];
            frag[j] = f2bf(v);
        }
    } else if (b < 100) {
        int u = b - 60, e = u / 8, ks = (u % 8) / 4, nt = u % 4;
        int n = nt * 16 + nl;
#pragma unroll
        for (int j = 0; j < 8; j++) {
            int k = ks * 32 + quad * 8 + j;
            frag[j] = f2bf((e < 4) ? W2[(e * 64 + k) * 64 + n] : cW2[k * 64 + n]);
        }
    } else if (b < 110) {
        int u = b - 100;
#pragma unroll
        for (int j = 0; j < 8; j++) {
            int ks = (u < 8) ? (u & 1) : (u - 8);
            int k  = ks * 32 + quad * 8 + j;
            float v;
            if (u < 8) { int ee = u >> 1; v = W3[(ee * 64 + k) * 16 + nl]; }
            else       { v = (nl == 0) ? cW3[k] : 0.f; }
            frag[j] = f2bf(v);
        }
    } else {
        // L2 bias frags: block = (net*4 + nt), value only at local k==0
        int u = b - 110, net = u / 4, nt = u % 4;
        int n = nt * 16 + nl;
#pragma unroll
        for (int j = 0; j < 8; j++) {
            float v = 0.f;
            if (quad == 0 && j == 0) v = (net < 4) ? b2[net * 64 + n] : cb2[n];
            frag[j] = f2bf(v);
        }
    }
    v8s pk = { frag[0], frag[1], frag[2], frag[3], frag[4], frag[5], frag[6], frag[7] };
    *(v8s*)(wp + (size_t)b * 512 + lane * 8) = pk;
}

// ---------------- fused main kernel ----------------

__global__ __launch_bounds__(256, 4) void main_kernel(
    const float* __restrict__ obs, const int* __restrict__ hete,
    const float* __restrict__ gp, const short* __restrict__ wp,
    const float* __restrict__ b3, const float* __restrict__ cb3,
    float* __restrict__ out)
{
    // union buffer: xs phase uses stride XS_STR, hs phase stride HS_STR.
    __shared__ __align__(16) short buf[128 * HS_STR];
    __shared__ int rowtok[128];   // sorted row -> local token
    __shared__ int wcnt[2][4];    // per-wave expert counts

    short* xs = buf;
    short* hs = buf;

    const int tid = threadIdx.x, lane = tid & 63, w = tid >> 6;
    const int ml = lane & 15, quad = lane >> 4;
    const int ts0 = blockIdx.x * NT;
    const int ltk = tid >> 1, hh = tid & 1;   // 2 threads per token

    // --- entry: issue ts0 input loads immediately (coalesced) ---
    float4 f[8];
    {
        const float4* src = (const float4*)(obs + ((size_t)ts0 * 128 + ltk) * 64 + hh * 32);
#pragma unroll
        for (int t = 0; t < 8; t++) f[t] = src[t];
    }
    int ec = hete[(size_t)ts0 * 128 + (tid & 127)];
    float g0, g1, g2, g3;
    {
        const float* gpb = gp + (size_t)ts0 * 4;
        g0 = gpb[0]; g1 = gpb[1]; g2 = gpb[2]; g3 = gpb[3];
    }
    // ts1 prefetch targets (filled during it==0 compute)
    float4 fn[8];
    int en = 0;
    float n0 = 0.f, n1 = 0.f, n2 = 0.f, n3 = 0.f;

    // token-uniform one-hot frag (ts-independent)
    v8s onef = (v8s){0,0,0,0,0,0,0,0};
    if (quad == 0) onef[0] = (short)0x3F80;

#pragma unroll
    for (int it = 0; it < NT; ++it) {
        const size_t tbase = (size_t)(ts0 + it) * 128;
        if (it) __syncthreads();   // hs (prev ts) free before xs overwrite

        // --- stage x UNSORTED: row = natural token id (no sort dependency) ---
        {
            int rb = ltk * XS_STR + hh * 32;
#pragma unroll
            for (int t = 0; t < 4; t++) {
                float4 a0 = f[2 * t], a1 = f[2 * t + 1];
                v8s pk = { f2bf(a0.x), f2bf(a0.y), f2bf(a0.z), f2bf(a0.w),
                           f2bf(a1.x), f2bf(a1.y), f2bf(a1.z), f2bf(a1.w) };
                *(v8s*)&xs[rb + t * 8] = pk;
            }
        }

        // --- 4-way stable partition of 128 tokens (waves 0,1) ---
        int e = ec, rank = 0;
        if (tid < 128) {
            unsigned long long ltm = (1ull << lane) - 1ull;
            unsigned long long m0 = __ballot(e == 0);
            unsigned long long m1 = __ballot(e == 1);
            unsigned long long m2 = __ballot(e == 2);
            unsigned long long m3 = __ballot(e == 3);
            if      (e == 0) rank = __popcll(m0 & ltm);
            else if (e == 1) rank = __popcll(m1 & ltm);
            else if (e == 2) rank = __popcll(m2 & ltm);
            else             rank = __popcll(m3 & ltm);
            if (lane == 0) {
                wcnt[w][0] = __popcll(m0); wcnt[w][1] = __popcll(m1);
                wcnt[w][2] = __popcll(m2); wcnt[w][3] = __popcll(m3);
            }
        }
        __syncthreads();   // sync_a: wcnt visible

        const int c0 = wcnt[0][0] + wcnt[1][0];
        const int c1 = wcnt[0][1] + wcnt[1][1];
        const int c2 = wcnt[0][2] + wcnt[1][2];
        const int sgs1 = __builtin_amdgcn_readfirstlane(c0);
        const int sgs2 = __builtin_amdgcn_readfirstlane(c0 + c1);
        const int sgs3 = __builtin_amdgcn_readfirstlane(c0 + c1 + c2);
        const int SG[5] = { 0, sgs1, sgs2, sgs3, 128 };

        if (tid < 128) {
            int gsE  = SEL4(e, 0, sgs1, sgs2, sgs3);
            int woff = (w == 1) ? wcnt[0][e] : 0;
            rowtok[gsE + woff + rank] = tid;
        }
        __syncthreads();   // sync_b: rowtok + xs staged

        // per-tile token ids into registers (static indexing)
        int tokR[8];
#pragma unroll
        for (int mt = 0; mt < 8; mt++) tokR[mt] = rowtok[mt * 16 + ml];

        // gfrag = x cols 64..95 (gp + 1.0 bias slot at k=68)
        v8s gfrag = (v8s){0,0,0,0,0,0,0,0};
        if (quad == 0) {
            gfrag[0] = f2bf(g0); gfrag[1] = f2bf(g1);
            gfrag[2] = f2bf(g2); gfrag[3] = f2bf(g3);
            gfrag[4] = (short)0x3F80;
        }

        // =================================================================
        // Layer 1: D = W^T X^T, K=96; ks=2 (gp+bias) folded into acc init.
        // =================================================================
        v4f accE[8], accC[8], fx[3];
        fx[0] = fx[1] = fx[2] = (v4f){0,0,0,0};

        {   // critic init (ks=2 + cb1)
            v8s cWg = *(const v8s*)(wp + (size_t)(14 * 4 + w) * 512 + lane * 8);
            v4f tC = __builtin_amdgcn_mfma_f32_16x16x32_bf16(cWg, gfrag, (v4f){0,0,0,0}, 0, 0, 0);
#pragma unroll
            for (int mt = 0; mt < 8; mt++) accC[mt] = tC;
        }
#pragma unroll
        for (int te = 0; te < 4; te++) {
            int lo = SG[te], hi = SG[te + 1];
            if (lo < hi) {
                v8s aW2 = *(const v8s*)(wp + (size_t)((te * 3 + 2) * 4 + w) * 512 + lane * 8);
                v4f tE = __builtin_amdgcn_mfma_f32_16x16x32_bf16(aW2, gfrag, (v4f){0,0,0,0}, 0, 0, 0);
#pragma unroll
                for (int mt = 0; mt < 8; mt++)
                    if (mt * 16 >= lo && mt * 16 < hi) accE[mt] = tE;
                if (te > 0 && (lo & 15)) fx[te - 1] = tE;
            }
        }

        v8s cf1[2];
#pragma unroll
        for (int ks = 0; ks < 2; ks++)
            cf1[ks] = *(const v8s*)(wp + (size_t)((12 + ks) * 4 + w) * 512 + lane * 8);

#pragma unroll
        for (int ks = 0; ks < 2; ks++) {
#pragma unroll
            for (int mt = 0; mt < 8; mt++) {
                v8s xb = *(const v8s*)&xs[tokR[mt] * XS_STR + ks * 32 + quad * 8];
                accC[mt] = __builtin_amdgcn_mfma_f32_16x16x32_bf16(cf1[ks], xb, accC[mt], 0, 0, 0);
            }
#pragma unroll
            for (int te = 0; te < 4; te++) {
                int lo = SG[te], hi = SG[te + 1];
                if (lo < hi) {
                    v8s aW = *(const v8s*)(wp + (size_t)((te * 3 + ks) * 4 + w) * 512 + lane * 8);
#pragma unroll
                    for (int mt = 0; mt < 8; mt++) {
                        if (mt * 16 >= lo && mt * 16 < hi) {
                            v8s xb = *(const v8s*)&xs[tokR[mt] * XS_STR + ks * 32 + quad * 8];
                            accE[mt] = __builtin_amdgcn_mfma_f32_16x16x32_bf16(aW, xb, accE[mt], 0, 0, 0);
                        }
                        if (te > 0 && (lo & 15) && (lo >> 4) == mt) {
                            v8s xb = *(const v8s*)&xs[tokR[mt] * XS_STR + ks * 32 + quad * 8];
                            fx[te - 1] = __builtin_amdgcn_mfma_f32_16x16x32_bf16(aW, xb, fx[te - 1], 0, 0, 0);
                        }
                    }
                }
            }
        }
        __syncthreads();   // sync_c: xs reads done; hs may overwrite (union)

        // --- prefetch ts1 inputs (issued early, consumed next iteration) ---
        if (it == 0) {
            const float4* srcn = (const float4*)(obs + ((size_t)(ts0 + 1) * 128 + ltk) * 64 + hh * 32);
#pragma unroll
            for (int t = 0; t < 8; t++) fn[t] = srcn[t];
            en = hete[(size_t)(ts0 + 1) * 128 + (tid & 127)];
            const float* gpn = gp + (size_t)(ts0 + 1) * 4;
            n0 = gpn[0]; n1 = gpn[1]; n2 = gpn[2]; n3 = gpn[3];
        }

        // h1 writes (bias already in acc): packed b64
        {
#pragma unroll
            for (int mt = 0; mt < 8; mt++) {
                int rb = (mt * 16 + ml) * HS_STR + w * 16 + quad * 4;
                *(v4s*)&hs[rb]      = pack4r(accE[mt]);
                *(v4s*)&hs[rb + 64] = pack4r(accC[mt]);
            }
#pragma unroll
            for (int bb = 0; bb < 3; bb++) {
                int lo = SG[bb + 1], hi = SG[bb + 2];
                if ((lo & 15) && lo < hi) {
                    int row  = (lo >> 4) * 16 + ml;
                    int erow = (row >= sgs1) + (row >= sgs2) + (row >= sgs3);
                    if (erow == bb + 1)
                        *(v4s*)&hs[row * HS_STR + w * 16 + quad * 4] = pack4r(fx[bb]);
                }
            }
        }
        __syncthreads();   // sync_d: h1 complete

        // =================================================================
        // Layer 2: K=64 (2 ks); bias folded in via one-hot frag MFMA init.
        // =================================================================
        v4f acc2E[8], acc2C[8], fx2[3];
        fx2[0] = fx2[1] = fx2[2] = (v4f){0,0,0,0};

        {   // critic bias init
            v8s cbf = *(const v8s*)(wp + WPB2_OFF + (size_t)(16 + w) * 512 + lane * 8);
            v4f tC = __builtin_amdgcn_mfma_f32_16x16x32_bf16(cbf, onef, (v4f){0,0,0,0}, 0, 0, 0);
#pragma unroll
            for (int mt = 0; mt < 8; mt++) acc2C[mt] = tC;
        }
#pragma unroll
        for (int te = 0; te < 4; te++) {
            int lo = SG[te], hi = SG[te + 1];
            if (lo < hi) {
                v8s bf = *(const v8s*)(wp + WPB2_OFF + (size_t)(te * 4 + w) * 512 + lane * 8);
                v4f tE = __builtin_amdgcn_mfma_f32_16x16x32_bf16(bf, onef, (v4f){0,0,0,0}, 0, 0, 0);
#pragma unroll
                for (int mt = 0; mt < 8; mt++)
                    if (mt * 16 >= lo && mt * 16 < hi) acc2E[mt] = tE;
                if (te > 0 && (lo & 15)) fx2[te - 1] = tE;
            }
        }

        v8s cf2[2];
#pragma unroll
        for (int ks = 0; ks < 2; ks++)
            cf2[ks] = *(const v8s*)(wp + WP2_OFF + (size_t)((8 + ks) * 4 + w) * 512 + lane * 8);

#pragma unroll
        for (int ks = 0; ks < 2; ks++) {
#pragma unroll
            for (int mt = 0; mt < 8; mt++) {
                v8s hC = *(const v8s*)&hs[(mt * 16 + ml) * HS_STR + 64 + ks * 32 + quad * 8];
                acc2C[mt] = __builtin_amdgcn_mfma_f32_16x16x32_bf16(cf2[ks], hC, acc2C[mt], 0, 0, 0);
            }
#pragma unroll
            for (int te = 0; te < 4; te++) {
                int lo = SG[te], hi = SG[te + 1];
                if (lo < hi) {
                    v8s aW = *(const v8s*)(wp + WP2_OFF + (size_t)((te * 2 + ks) * 4 + w) * 512 + lane * 8);
#pragma unroll
                    for (int mt = 0; mt < 8; mt++) {
                        if (mt * 16 >= lo && mt * 16 < hi) {
                            v8s hE = *(const v8s*)&hs[(mt * 16 + ml) * HS_STR + ks * 32 + quad * 8];
                            acc2E[mt] = __builtin_amdgcn_mfma_f32_16x16x32_bf16(aW, hE, acc2E[mt], 0, 0, 0);
                        }
                        if (te > 0 && (lo & 15) && (lo >> 4) == mt) {
                            v8s hE = *(const v8s*)&hs[(mt * 16 + ml) * HS_STR + ks * 32 + quad * 8];
                            fx2[te - 1] = __builtin_amdgcn_mfma_f32_16x16x32_bf16(aW, hE, fx2[te - 1], 0, 0, 0);
                        }
                    }
                }
            }
        }
        __syncthreads();   // sync_e: h1 reads done

        {
#pragma unroll
            for (int mt = 0; mt < 8; mt++) {
                int rb = (mt * 16 + ml) * HS_STR + w * 16 + quad * 4;
                *(v4s*)&hs[rb]      = pack4r(acc2E[mt]);
                *(v4s*)&hs[rb + 64] = pack4r(acc2C[mt]);
            }
#pragma unroll
            for (int bb = 0; bb < 3; bb++) {
                int lo = SG[bb + 1], hi = SG[bb + 2];
                if ((lo & 15) && lo < hi) {
                    int row  = (lo >> 4) * 16 + ml;
                    int erow = (row >= sgs1) + (row >= sgs2) + (row >= sgs3);
                    if (erow == bb + 1)
                        *(v4s*)&hs[row * HS_STR + w * 16 + quad * 4] = pack4r(fx2[bb]);
                }
            }
        }
        __syncthreads();   // sync_f: h2 complete

        // =================================================================
        // Layer 3: wave w owns tiles {w, w+4}; critic value via padded M.
        // =================================================================
        v4f accL[2], accV[2];
#pragma unroll
        for (int j = 0; j < 2; j++) { accL[j] = (v4f){0,0,0,0}; accV[j] = (v4f){0,0,0,0}; }

#pragma unroll
        for (int ks = 0; ks < 2; ks++) {
            v8s aV = *(const v8s*)(wp + WP3_OFF + (size_t)(8 + ks) * 512 + lane * 8);
#pragma unroll
            for (int j = 0; j < 2; j++) {
                int mt = w + 4 * j;
                int te = (mt * 16 >= sgs1) + (mt * 16 >= sgs2) + (mt * 16 >= sgs3);
                v8s aW = *(const v8s*)(wp + WP3_OFF + (size_t)(te * 2 + ks) * 512 + lane * 8);
                v8s hE = *(const v8s*)&hs[(mt * 16 + ml) * HS_STR + ks * 32 + quad * 8];
                v8s hC = *(const v8s*)&hs[(mt * 16 + ml) * HS_STR + 64 + ks * 32 + quad * 8];
                accL[j] = __builtin_amdgcn_mfma_f32_16x16x32_bf16(aW, hE, accL[j], 0, 0, 0);
                accV[j] = __builtin_amdgcn_mfma_f32_16x16x32_bf16(aV, hC, accV[j], 0, 0, 0);
            }
        }

        v4f fxL[3];
#pragma unroll
        for (int bb = 0; bb < 3; bb++) {
            fxL[bb] = (v4f){0,0,0,0};
            int lo = SG[bb + 1], hi = SG[bb + 2];
            int mtb = lo >> 4;
            if ((lo & 15) && lo < hi && (mtb & 3) == w) {
#pragma unroll
                for (int ks = 0; ks < 2; ks++) {
                    v8s aW = *(const v8s*)(wp + WP3_OFF + (size_t)((bb + 1) * 2 + ks) * 512 + lane * 8);
                    v8s hE = *(const v8s*)&hs[(mtb * 16 + ml) * HS_STR + ks * 32 + quad * 8];
                    fxL[bb] = __builtin_amdgcn_mfma_f32_16x16x32_bf16(aW, hE, fxL[bb], 0, 0, 0);
                }
            }
        }

        // --- epilogue: dwordx4 logits store + value ---
        {
            float cb3v = cb3[0];
#pragma unroll
            for (int j = 0; j < 2; j++) {
                int mt = w + 4 * j;
                int te = (mt * 16 >= sgs1) + (mt * 16 >= sgs2) + (mt * 16 >= sgs3);
                int row = mt * 16 + ml;
                int erow = (row >= sgs1) + (row >= sgs2) + (row >= sgs3);
                int tk = rowtok[row];
                float* o = out + (tbase + (size_t)tk) * 17;
                if (erow == te) {
                    v4fa b3v = *(const v4fa*)(b3 + te * 16 + quad * 4);
                    v4fa ov = { accL[j][0] + b3v[0], accL[j][1] + b3v[1],
                                accL[j][2] + b3v[2], accL[j][3] + b3v[3] };
                    *(v4fa*)(o + quad * 4) = ov;
                }
                if (quad == 0) o[16] = accV[j][0] + cb3v;
            }
#pragma unroll
            for (int bb = 0; bb < 3; bb++) {
                int lo = SG[bb + 1], hi = SG[bb + 2];
                int mtb = lo >> 4;
                if ((lo & 15) && lo < hi && (mtb & 3) == w) {
                    int row = mtb * 16 + ml;
                    int erow = (row >= sgs1) + (row >= sgs2) + (row >= sgs3);
                    if (erow == bb + 1) {
                        v4fa b3v = *(const v4fa*)(b3 + (bb + 1) * 16 + quad * 4);
                        int tk = rowtok[row];
                        float* o = out + (tbase + (size_t)tk) * 17;
                        v4fa ov = { fxL[bb][0] + b3v[0], fxL[bb][1] + b3v[1],
                                    fxL[bb][2] + b3v[2], fxL[bb][3] + b3v[3] };
                        *(v4fa*)(o + quad * 4) = ov;
                    }
                }
            }
        }

        // rotate prefetched inputs into current slots
        if (it == 0) {
#pragma unroll
            for (int t = 0; t < 8; t++) f[t] = fn[t];
            ec = en; g0 = n0; g1 = n1; g2 = n2; g3 = n3;
        }
    }
}

// ---------------------------------------------------------------------------

extern "C" void kernel_launch(void* const* d_in, const int* in_sizes, int n_in,
                              void* d_out, int out_size, void* d_ws, size_t ws_size,
                              hipStream_t stream) {
    const float* obs = (const float*)d_in[0];
    const int*  hete = (const int*)d_in[1];
    const float* gp  = (const float*)d_in[2];
    const float* W1  = (const float*)d_in[3];
    const float* b1  = (const float*)d_in[4];
    const float* W2  = (const float*)d_in[5];
    const float* b2  = (const float*)d_in[6];
    const float* W3  = (const float*)d_in[7];
    const float* b3  = (const float*)d_in[8];
    const float* cW1 = (const float*)d_in[9];
    const float* cb1 = (const float*)d_in[10];
    const float* cW2 = (const float*)d_in[11];
    const float* cb2 = (const float*)d_in[12];
    const float* cW3 = (const float*)d_in[13];
    const float* cb3 = (const float*)d_in[14];
    float* out = (float*)d_out;

    short* wp = (short*)d_ws;   // 130 * 512 shorts = 133120 B

    prep_kernel<<<130,  64, 0, stream>>>(W1, cW1, W2, cW2, W3, cW3,
                                         b1, cb1, b2, cb2, wp);
    main_kernel<<<1024, 256, 0, stream>>>(obs, hete, gp, wp, b3, cb3, out);
}

// Round 6
// 161.339 us; speedup vs baseline: 1.3869x; 1.3869x over previous
//
#include <hip/hip_runtime.h>
#include <stdint.h>

// ---------------------------------------------------------------------------
// HeteNet round 8: barrier-free main pipeline.
// After a 2-barrier sort prologue, each wave owns tiles {2w, 2w+1} (16 sorted
// tokens each) END-TO-END: L1 reads x from LDS; L1->L2 and L2->L3 feature
// exchanges go through a per-WAVE private LDS scratch (same-wave ds ordering,
// no __syncthreads). Expert boundaries handled by fix-up MFMA chains +
// per-lane cndmask selects. Carries verified algebra: gfrag bias-fold,
// one-hot L2-bias MFMA, transposed dataflow, native bf16 converts.
// Kernels: prep -> main. ws holds wp (130 KiB).
// ---------------------------------------------------------------------------

typedef float v4f __attribute__((ext_vector_type(4)));
typedef short v8s __attribute__((ext_vector_type(8)));
typedef short v4s __attribute__((ext_vector_type(4)));
typedef float v4fa __attribute__((ext_vector_type(4), aligned(4)));

#define XS_STR 72      // row stride (shorts) = 144 B: 16B-aligned, conflict-benign
#define SW_NET 1152    // scratch net offset (16 tok * 72)
#define WP2_OFF  30720 // 60 frag-blocks * 512 shorts
#define WP3_OFF  51200 // + 40 * 512
#define WPB2_OFF 56320 // + 10 * 512 ; L2-bias frags

#define SEL4(te, a0, a1, a2, a3) \
    ((te) < 2 ? ((te) == 0 ? (a0) : (a1)) : ((te) == 2 ? (a2) : (a3)))

#define MFMA __builtin_amdgcn_mfma_f32_16x16x32_bf16
#define WFRAG(blk) (*(const v8s*)(wp + (size_t)(blk) * 512 + lane * 8))

static __device__ __forceinline__ short f2bf(float f) {
    union { __bf16 b; short s; } u;
    u.b = (__bf16)f;   // native RNE convert
    return u.s;
}

static __device__ __forceinline__ v4s pack4r(const v4f a) {
    v4s r;
    r[0] = f2bf(fmaxf(a[0], 0.f));
    r[1] = f2bf(fmaxf(a[1], 0.f));
    r[2] = f2bf(fmaxf(a[2], 0.f));
    r[3] = f2bf(fmaxf(a[3], 0.f));
    return r;
}

// ---------------- weight prep: fragment-ready bf16 layout ----------------
// Frag-block = 512 shorts: lane l holds out-feat n=l&15, k=(l>>4)*8+j.
// L1 frags carry bias at k==68 (multiplied by gfrag's 1.0 slot).
// WPB2 region: L2 bias frags, nonzero only at local k==0 (one-hot onef).
__global__ void prep_kernel(const float* __restrict__ W1, const float* __restrict__ cW1,
                            const float* __restrict__ W2, const float* __restrict__ cW2,
                            const float* __restrict__ W3, const float* __restrict__ cW3,
                            const float* __restrict__ b1, const float* __restrict__ cb1,
                            const float* __restrict__ b2, const float* __restrict__ cb2,
                            short* __restrict__ wp) {
    int b = blockIdx.x, lane = threadIdx.x;
    int nl = lane & 15, quad = lane >> 4;
    short frag[8];
    if (b < 60) {
        int e = b / 12, rem = b % 12, ks = rem / 4, nt = rem % 4;
        int n = nt * 16 + nl;
#pragma unroll
        for (int j = 0; j < 8; j++) {
            int k = ks * 32 + quad * 8 + j;
            float v = 0.f;
            if (k < 68)       v = (e < 4) ? W1[(e * 68 + k) * 64 + n] : cW1[k * 64 + n];
            else if (k == 68) v = (e < 4) ? b1[e * 64 + n] : cb1[n];
            frag[j] = f2bf(v);
        }
    } else if (b < 100) {
        int u = b - 60, e = u / 8, ks = (u % 8) / 4, nt = u % 4;
        int n = nt * 16 + nl;
#pragma unroll
        for (int j = 0; j < 8; j++) {
            int k = ks * 32 + quad * 8 + j;
            frag[j] = f2bf((e < 4) ? W2[(e * 64 + k) * 64 + n] : cW2[k * 64 + n]);
        }
    } else if (b < 110) {
        int u = b - 100;
#pragma unroll
        for (int j = 0; j < 8; j++) {
            int ks = (u < 8) ? (u & 1) : (u - 8);
            int k  = ks * 32 + quad * 8 + j;
            float v;
            if (u < 8) { int ee = u >> 1; v = W3[(ee * 64 + k) * 16 + nl]; }
            else       { v = (nl == 0) ? cW3[k] : 0.f; }
            frag[j] = f2bf(v);
        }
    } else {
        int u = b - 110, net = u / 4, nt = u % 4;
        int n = nt * 16 + nl;
#pragma unroll
        for (int j = 0; j < 8; j++) {
            float v = 0.f;
            if (quad == 0 && j == 0) v = (net < 4) ? b2[net * 64 + n] : cb2[n];
            frag[j] = f2bf(v);
        }
    }
    v8s pk = { frag[0], frag[1], frag[2], frag[3], frag[4], frag[5], frag[6], frag[7] };
    *(v8s*)(wp + (size_t)b * 512 + lane * 8) = pk;
}

// ---------------- fused main kernel ----------------

__global__ __launch_bounds__(256, 4) void main_kernel(
    const float* __restrict__ obs, const int* __restrict__ hete,
    const float* __restrict__ gp, const short* __restrict__ wp,
    const float* __restrict__ b3, const float* __restrict__ cb3,
    float* __restrict__ out)
{
    // xs: 128 tok x 72 shorts = 18432 B.
    // per-wave scratch: 2 nets x 16 tok x 72 shorts = 4608 B x 4 waves.
    // total ~37.4 KB -> 4 blocks/CU.
    __shared__ __align__(16) short buf[9216 + 4 * 2304];
    __shared__ int rowtok[128];   // sorted row -> local token
    __shared__ int wcnt[2][4];    // per-wave expert counts

    short* xs = buf;

    const int tid = threadIdx.x, lane = tid & 63, w = tid >> 6;
    const int ml = lane & 15, quad = lane >> 4;
    const size_t base = (size_t)blockIdx.x * 128;
    short* sw = buf + 9216 + w * 2304;   // wave-private scratch

    // --- entry: issue obs loads (coalesced contiguous 32 KB/block) ---
    const int ltk = tid >> 1, hh = tid & 1;
    const float4* src = (const float4*)(obs + (base + ltk) * 64 + hh * 32);
    float4 f[8];
#pragma unroll
    for (int t = 0; t < 8; t++) f[t] = src[t];

    const float* gpb = gp + (size_t)blockIdx.x * 4;
    float g0 = gpb[0], g1 = gpb[1], g2 = gpb[2], g3 = gpb[3];

    // --- 4-way stable partition of 128 tokens (waves 0,1) ---
    int e = 0, rank = 0;
    if (tid < 128) {
        e = hete[base + tid];
        unsigned long long ltm = (1ull << lane) - 1ull;
        unsigned long long m0 = __ballot(e == 0);
        unsigned long long m1 = __ballot(e == 1);
        unsigned long long m2 = __ballot(e == 2);
        unsigned long long m3 = __ballot(e == 3);
        if      (e == 0) rank = __popcll(m0 & ltm);
        else if (e == 1) rank = __popcll(m1 & ltm);
        else if (e == 2) rank = __popcll(m2 & ltm);
        else             rank = __popcll(m3 & ltm);
        if (lane == 0) {
            wcnt[w][0] = __popcll(m0); wcnt[w][1] = __popcll(m1);
            wcnt[w][2] = __popcll(m2); wcnt[w][3] = __popcll(m3);
        }
    }
    __syncthreads();   // bar_a: wcnt visible

    const int c0 = wcnt[0][0] + wcnt[1][0];
    const int c1 = wcnt[0][1] + wcnt[1][1];
    const int c2 = wcnt[0][2] + wcnt[1][2];
    const int sgs1 = __builtin_amdgcn_readfirstlane(c0);
    const int sgs2 = __builtin_amdgcn_readfirstlane(c0 + c1);
    const int sgs3 = __builtin_amdgcn_readfirstlane(c0 + c1 + c2);
    const int SGa[5] = { 0, sgs1, sgs2, sgs3, 128 };

    if (tid < 128) {
        int gsE  = SEL4(e, 0, sgs1, sgs2, sgs3);
        int woff = (w == 1) ? wcnt[0][e] : 0;
        rowtok[gsE + woff + rank] = tid;
    }

    // --- stage x UNSORTED (row = token id); overlaps nothing else needed ---
    {
        int rb = ltk * XS_STR + hh * 32;
#pragma unroll
        for (int t = 0; t < 4; t++) {
            float4 a0 = f[2 * t], a1 = f[2 * t + 1];
            v8s pk = { f2bf(a0.x), f2bf(a0.y), f2bf(a0.z), f2bf(a0.w),
                       f2bf(a1.x), f2bf(a1.y), f2bf(a1.z), f2bf(a1.w) };
            *(v8s*)&xs[rb + t * 8] = pk;
        }
    }
    __syncthreads();   // bar_b: rowtok + xs staged. LAST BLOCK BARRIER.

    // token-uniform B-frags
    v8s gfrag = (v8s){0,0,0,0,0,0,0,0};
    v8s onef  = (v8s){0,0,0,0,0,0,0,0};
    if (quad == 0) {
        gfrag[0] = f2bf(g0); gfrag[1] = f2bf(g1);
        gfrag[2] = f2bf(g2); gfrag[3] = f2bf(g3);
        gfrag[4] = (short)0x3F80;   // 1.0 -> multiplies L1 bias row k=68
        onef[0]  = (short)0x3F80;
    }
    const float cb3v = cb3[0];

    // =====================================================================
    // Per-wave pipeline over its 2 tiles; no block barriers from here on.
    // =====================================================================
#pragma unroll
    for (int ntl = 0; ntl < 2; ++ntl) {
        const int t   = 2 * w + ntl;
        const int r0  = t * 16;
        const int teT = (r0 >= sgs1) + (r0 >= sgs2) + (r0 >= sgs3);
        const int pos = r0 + ml;
        const int e_l = (pos >= sgs1) + (pos >= sgs2) + (pos >= sgs3);
        const int tok = rowtok[pos];

        // x B-frags for this tile (ks = 0,1)
        v8s xb0 = *(const v8s*)&xs[tok * XS_STR + quad * 8];
        v8s xb1 = *(const v8s*)&xs[tok * XS_STR + 32 + quad * 8];

        // ---------------- Layer 1 (K=96: 2 LDS ks + gfrag init) ----------
        v4f hE[4], aC[4];
#pragma unroll
        for (int m = 0; m < 4; m++) {
            v4f v = MFMA(WFRAG((teT * 3 + 2) * 4 + m), gfrag, (v4f){0,0,0,0}, 0, 0, 0);
            v = MFMA(WFRAG((teT * 3 + 0) * 4 + m), xb0, v, 0, 0, 0);
            v = MFMA(WFRAG((teT * 3 + 1) * 4 + m), xb1, v, 0, 0, 0);
            hE[m] = v;
            v4f c = MFMA(WFRAG(14 * 4 + m), gfrag, (v4f){0,0,0,0}, 0, 0, 0);
            c = MFMA(WFRAG(12 * 4 + m), xb0, c, 0, 0, 0);
            c = MFMA(WFRAG(13 * 4 + m), xb1, c, 0, 0, 0);
            aC[m] = c;
        }
        // boundary fix-ups: recompute with next expert, per-lane select
#pragma unroll
        for (int bb = 0; bb < 3; bb++) {
            const int lo = SGa[bb + 1];
            if ((lo & 15) && (lo >> 4) == t && lo < SGa[bb + 2]) {
                const int te2 = bb + 1;
#pragma unroll
                for (int m = 0; m < 4; m++) {
                    v4f v = MFMA(WFRAG((te2 * 3 + 2) * 4 + m), gfrag, (v4f){0,0,0,0}, 0, 0, 0);
                    v = MFMA(WFRAG((te2 * 3 + 0) * 4 + m), xb0, v, 0, 0, 0);
                    v = MFMA(WFRAG((te2 * 3 + 1) * 4 + m), xb1, v, 0, 0, 0);
                    hE[m] = (e_l == te2) ? v : hE[m];
                }
            }
        }
        // h1 -> wave-private scratch (same-wave ordering; no barrier)
#pragma unroll
        for (int m = 0; m < 4; m++) {
            *(v4s*)&sw[ml * XS_STR + m * 16 + quad * 4]          = pack4r(hE[m]);
            *(v4s*)&sw[SW_NET + ml * XS_STR + m * 16 + quad * 4] = pack4r(aC[m]);
        }

        // ---------------- Layer 2 (K=64; one-hot bias init) --------------
        v8s hbE0 = *(const v8s*)&sw[ml * XS_STR + quad * 8];
        v8s hbE1 = *(const v8s*)&sw[ml * XS_STR + 32 + quad * 8];
        v8s hbC0 = *(const v8s*)&sw[SW_NET + ml * XS_STR + quad * 8];
        v8s hbC1 = *(const v8s*)&sw[SW_NET + ml * XS_STR + 32 + quad * 8];

        v4f h2E[4], bC[4];
#pragma unroll
        for (int m = 0; m < 4; m++) {
            v4f v = MFMA(WFRAG(WPB2_OFF / 512 + teT * 4 + m), onef, (v4f){0,0,0,0}, 0, 0, 0);
            v = MFMA(WFRAG(WP2_OFF / 512 + (teT * 2 + 0) * 4 + m), hbE0, v, 0, 0, 0);
            v = MFMA(WFRAG(WP2_OFF / 512 + (teT * 2 + 1) * 4 + m), hbE1, v, 0, 0, 0);
            h2E[m] = v;
            v4f c = MFMA(WFRAG(WPB2_OFF / 512 + 16 + m), onef, (v4f){0,0,0,0}, 0, 0, 0);
            c = MFMA(WFRAG(WP2_OFF / 512 + (8 + 0) * 4 + m), hbC0, c, 0, 0, 0);
            c = MFMA(WFRAG(WP2_OFF / 512 + (8 + 1) * 4 + m), hbC1, c, 0, 0, 0);
            bC[m] = c;
        }
#pragma unroll
        for (int bb = 0; bb < 3; bb++) {
            const int lo = SGa[bb + 1];
            if ((lo & 15) && (lo >> 4) == t && lo < SGa[bb + 2]) {
                const int te2 = bb + 1;
#pragma unroll
                for (int m = 0; m < 4; m++) {
                    v4f v = MFMA(WFRAG(WPB2_OFF / 512 + te2 * 4 + m), onef, (v4f){0,0,0,0}, 0, 0, 0);
                    v = MFMA(WFRAG(WP2_OFF / 512 + (te2 * 2 + 0) * 4 + m), hbE0, v, 0, 0, 0);
                    v = MFMA(WFRAG(WP2_OFF / 512 + (te2 * 2 + 1) * 4 + m), hbE1, v, 0, 0, 0);
                    h2E[m] = (e_l == te2) ? v : h2E[m];
                }
            }
        }
        // h2 -> scratch (overwrite; reads above already in registers)
#pragma unroll
        for (int m = 0; m < 4; m++) {
            *(v4s*)&sw[ml * XS_STR + m * 16 + quad * 4]          = pack4r(h2E[m]);
            *(v4s*)&sw[SW_NET + ml * XS_STR + m * 16 + quad * 4] = pack4r(bC[m]);
        }

        // ---------------- Layer 3 (M=16 logits; critic padded) -----------
        v8s h2E0 = *(const v8s*)&sw[ml * XS_STR + quad * 8];
        v8s h2E1 = *(const v8s*)&sw[ml * XS_STR + 32 + quad * 8];
        v8s h2C0 = *(const v8s*)&sw[SW_NET + ml * XS_STR + quad * 8];
        v8s h2C1 = *(const v8s*)&sw[SW_NET + ml * XS_STR + 32 + quad * 8];

        v4f accL = MFMA(WFRAG(WP3_OFF / 512 + teT * 2 + 0), h2E0, (v4f){0,0,0,0}, 0, 0, 0);
        accL     = MFMA(WFRAG(WP3_OFF / 512 + teT * 2 + 1), h2E1, accL, 0, 0, 0);
        v4f accV = MFMA(WFRAG(WP3_OFF / 512 + 8), h2C0, (v4f){0,0,0,0}, 0, 0, 0);
        accV     = MFMA(WFRAG(WP3_OFF / 512 + 9), h2C1, accV, 0, 0, 0);

#pragma unroll
        for (int bb = 0; bb < 3; bb++) {
            const int lo = SGa[bb + 1];
            if ((lo & 15) && (lo >> 4) == t && lo < SGa[bb + 2]) {
                const int te2 = bb + 1;
                v4f v = MFMA(WFRAG(WP3_OFF / 512 + te2 * 2 + 0), h2E0, (v4f){0,0,0,0}, 0, 0, 0);
                v     = MFMA(WFRAG(WP3_OFF / 512 + te2 * 2 + 1), h2E1, v, 0, 0, 0);
#pragma unroll
                for (int rr = 0; rr < 4; rr++)
                    accL[rr] = (e_l == te2) ? v[rr] : accL[rr];
            }
        }

        // ---------------- epilogue: per-lane expert bias + store ----------
        {
            const v4fa b3v = *(const v4fa*)(b3 + e_l * 16 + quad * 4);
            float* o = out + (base + (size_t)tok) * 17;
            v4fa ov = { accL[0] + b3v[0], accL[1] + b3v[1],
                        accL[2] + b3v[2], accL[3] + b3v[3] };
            *(v4fa*)(o + quad * 4) = ov;
            if (quad == 0) o[16] = accV[0] + cb3v;
        }
    }
}

// ---------------------------------------------------------------------------

extern "C" void kernel_launch(void* const* d_in, const int* in_sizes, int n_in,
                              void* d_out, int out_size, void* d_ws, size_t ws_size,
                              hipStream_t stream) {
    const float* obs = (const float*)d_in[0];
    const int*  hete = (const int*)d_in[1];
    const float* gp  = (const float*)d_in[2];
    const float* W1  = (const float*)d_in[3];
    const float* b1  = (const float*)d_in[4];
    const float* W2  = (const float*)d_in[5];
    const float* b2  = (const float*)d_in[6];
    const float* W3  = (const float*)d_in[7];
    const float* b3  = (const float*)d_in[8];
    const float* cW1 = (const float*)d_in[9];
    const float* cb1 = (const float*)d_in[10];
    const float* cW2 = (const float*)d_in[11];
    const float* cb2 = (const float*)d_in[12];
    const float* cW3 = (const float*)d_in[13];
    const float* cb3 = (const float*)d_in[14];
    float* out = (float*)d_out;

    short* wp = (short*)d_ws;   // 130 * 512 shorts = 133120 B

    prep_kernel<<<130,  64, 0, stream>>>(W1, cW1, W2, cW2, W3, cW3,
                                         b1, cb1, b2, cb2, wp);
    main_kernel<<<2048, 256, 0, stream>>>(obs, hete, gp, wp, b3, cb3, out);
}